// Round 10
// baseline (276.767 us; speedup 1.0000x reference)
//
#include <hip/hip_runtime.h>
#include <math.h>

#define N_NODES 100000
#define N_EDGES 500000
#define NGRP    31250        // N_EDGES/16
#define NTBL    8000000      // NGRP * 256

#define CHUNK   400          // nodes per owner block
#define NOWN    250          // 250*400 = 100000 exactly

typedef float f32x4 __attribute__((ext_vector_type(4)));  // nontemporal-safe

// Workspace layout (bytes):
#define OFF_ACC   0          // double
#define OFF_GCNT  16         // uint[250]
#define OFF_QBASE 1024       // uint[251]
#define OFF_QCUR  2048       // uint[250]
#define OFF_CV    4096       // fallback: float[N][16] 6.4MB | single: pos_h/pos_t (4MB)
#define OFF_TP    6404096    // uchar[E]
#define OFF_XT    6904096    // float[N][16]  6.4MB
#define OFF_TBL   13304096   // uchar[8M]
#define OFF_GQ    21304096   // uint[1M]      4MB
#define OFF_EMB   25304096   // emb buffer (64MB in single-chunk path)
#define EMB_BYTES 64000000ull

__device__ __forceinline__ unsigned owner_of(int n) {
    // floor(n/400) = floor((n>>4)/25); magic /25
    return (unsigned)(((unsigned long long)((unsigned)n >> 4) * 1374389535ull) >> 35);
}

// ---- pass 1: per-owner incidence histogram (+ tp bytes) ----
__global__ __launch_bounds__(1024) void k_hist(
    const int* __restrict__ src, const int* __restrict__ dst,
    const int* __restrict__ et, unsigned char* __restrict__ tp,
    unsigned* __restrict__ gcnt) {
    __shared__ unsigned hist[NOWN];
    for (int i = threadIdx.x; i < NOWN; i += 1024) hist[i] = 0;
    __syncthreads();
    int base = blockIdx.x * 2048;
#pragma unroll
    for (int k = 0; k < 2; ++k) {
        int e = base + k * 1024 + (int)threadIdx.x;
        if (e < N_EDGES) {
            int s = src[e], d = dst[e];
            tp[e] = (unsigned char)(et[s] * 8 + et[d]);
            atomicAdd(&hist[owner_of(s)], 1u);
            atomicAdd(&hist[owner_of(d)], 1u);
        }
    }
    __syncthreads();
    for (int i = threadIdx.x; i < NOWN; i += 1024)
        if (hist[i]) atomicAdd(&gcnt[i], hist[i]);
}

// ---- exclusive prefix over 250 counts ----
__global__ void k_prefix(const unsigned* __restrict__ gcnt,
                         unsigned* __restrict__ qbase, unsigned* __restrict__ qcur) {
    __shared__ unsigned v[256];
    int t = threadIdx.x;
    v[t] = (t < NOWN) ? gcnt[t] : 0u;
    __syncthreads();
    unsigned my = v[t];
#pragma unroll
    for (int off = 1; off < 256; off <<= 1) {
        unsigned add = (t >= off) ? v[t - off] : 0u;
        __syncthreads();
        v[t] += add;
        __syncthreads();
    }
    if (t < NOWN) {
        unsigned excl = v[t] - my;
        qbase[t] = excl; qcur[t] = excl;
    }
    if (t == NOWN) qbase[NOWN] = v[NOWN - 1];
}

// ---- pass 2: place incidences; record each incidence's queue position ----
__global__ __launch_bounds__(1024) void k_place(
    const int* __restrict__ src, const int* __restrict__ dst,
    unsigned* __restrict__ qcur, unsigned* __restrict__ gq,
    unsigned* __restrict__ pos_h, unsigned* __restrict__ pos_t) {
    __shared__ unsigned hist[NOWN];
    __shared__ unsigned lcur[NOWN];
    for (int i = threadIdx.x; i < NOWN; i += 1024) hist[i] = 0;
    __syncthreads();
    int base = blockIdx.x * 2048;
#pragma unroll
    for (int k = 0; k < 2; ++k) {
        int e = base + k * 1024 + (int)threadIdx.x;
        if (e < N_EDGES) {
            atomicAdd(&hist[owner_of(src[e])], 1u);
            atomicAdd(&hist[owner_of(dst[e])], 1u);
        }
    }
    __syncthreads();
    for (int i = threadIdx.x; i < NOWN; i += 1024)
        lcur[i] = hist[i] ? atomicAdd(&qcur[i], hist[i]) : 0u;
    __syncthreads();
#pragma unroll
    for (int k = 0; k < 2; ++k) {
        int e = base + k * 1024 + (int)threadIdx.x;
        if (e < N_EDGES) {
            int s = src[e], d = dst[e];
            unsigned os = owner_of(s), od = owner_of(d);
            unsigned ps = atomicAdd(&lcur[os], 1u);
            gq[ps] = (unsigned)e | ((unsigned)(s - (int)os * CHUNK) << 19);
            pos_h[e] = ps;
            unsigned pd = atomicAdd(&lcur[od], 1u);
            gq[pd] = (unsigned)e | ((unsigned)(d - (int)od * CHUNK) << 19) | (1u << 28);
            pos_t[e] = pd;
        }
    }
}

// ---- per-owner: deg from tail entries, then xT = reps * deg^-1/2 ----
__global__ __launch_bounds__(1024) void k_degxT(
    const unsigned* __restrict__ qbase, const unsigned* __restrict__ gq,
    const float* __restrict__ reps, float* __restrict__ xT) {
    __shared__ unsigned dh[CHUNK];
    for (int i = threadIdx.x; i < CHUNK; i += 1024) dh[i] = 0;
    __syncthreads();
    int o = blockIdx.x;
    unsigned lo = qbase[o], hi = qbase[o + 1];
    for (unsigned i = lo + threadIdx.x; i < hi; i += 1024) {
        unsigned ent = gq[i];
        if (ent >> 28) atomicAdd(&dh[(ent >> 19) & 511u], 1u);
    }
    __syncthreads();
    int nbase = o * CHUNK;
    for (int idx = threadIdx.x; idx < CHUNK; idx += 1024) {
        int n = nbase + idx;
        unsigned dg = dh[idx];
        float inv = dg ? 1.0f / sqrtf((float)dg) : 0.0f;
        float v[16];
#pragma unroll
        for (int j = 0; j < 16; ++j) v[j] = reps[j * N_NODES + n] * inv;
        float4* outp = (float4*)(xT + (size_t)n * 16);
#pragma unroll
        for (int j4 = 0; j4 < 4; ++j4)
            outp[j4] = make_float4(v[4*j4], v[4*j4+1], v[4*j4+2], v[4*j4+3]);
    }
}

// ---- tbl[E4][q] = tp[e2(q,E4)]:  u = 2q+E4; e2 = 1953q + (u>>4) ----
__global__ __launch_bounds__(256) void k_tbl(const unsigned char* __restrict__ tp,
                                             unsigned char* __restrict__ tbl) {
    int idx = blockIdx.x * 256 + (int)threadIdx.x;
    int E4 = idx >> 8, q = idx & 255;
    int u = 2 * q + E4;
    int e2 = 1953 * q + (u >> 4);
    tbl[idx] = tp[e2];
}

// ---- shared core of the wave-cooperative embedding ----
// head_maps[i,j,e] = RM[t][a][b]; q=16i+j, b=e&15, a=(2j+grp)&15, t=tbl[grp][q]
// (tail: byte-swapped t, x from dst). Wave: lanes=(b, ig), lane's i = 4*ig+ip.
__device__ __forceinline__ f32x4 emb_core(
    int grp, int role, int b, int ig, int node,
    const unsigned char* __restrict__ tbl, const float* __restrict__ rm,
    const float* __restrict__ xT) {
    float xs[16];
    const float4* xp = (const float4*)(xT + (size_t)node * 16);
#pragma unroll
    for (int j4 = 0; j4 < 4; ++j4) {
        float4 v = xp[j4];
        xs[4*j4] = v.x; xs[4*j4+1] = v.y; xs[4*j4+2] = v.z; xs[4*j4+3] = v.w;
    }
    unsigned w[16];
    const uint4* tr4 = (const uint4*)(tbl + (size_t)grp * 256 + ig * 64);
#pragma unroll
    for (int ip = 0; ip < 4; ++ip) {
        uint4 u = tr4[ip];
        w[ip*4+0] = u.x; w[ip*4+1] = u.y; w[ip*4+2] = u.z; w[ip*4+3] = u.w;
    }
    if (role) {   // byte-parallel type-pair swap: t' = ((t&7)<<3)|(t>>3)
#pragma unroll
        for (int c = 0; c < 16; ++c)
            w[c] = ((w[c] & 0x07070707u) << 3) | ((w[c] >> 3) & 0x07070707u);
    }
    unsigned vab[16];
#pragma unroll
    for (int jj = 0; jj < 16; ++jj)
        vab[jj] = ((unsigned)((2 * jj + grp) & 15) << 4) | (unsigned)b;

    f32x4 h;
#pragma unroll
    for (int ip = 0; ip < 4; ++ip) {
        float hacc = 0.f;
#pragma unroll
        for (int jj = 0; jj < 16; ++jj) {
            unsigned t = (w[ip*4 + (jj >> 2)] >> ((jj & 3) * 8)) & 255u;
            unsigned idx = ((t << 8) + vab[jj]) ^ (t & 31u);
            hacc += rm[idx] * xs[jj];
        }
        h[ip] = hacc;
    }
    return h;
}

// ---- single-chunk path: embeddings stored at their QUEUE POSITION ----
__global__ __launch_bounds__(1024) void k_emb2(
    const int* __restrict__ src, const int* __restrict__ dst,
    const unsigned char* __restrict__ tbl, const float* __restrict__ rmg,
    const float* __restrict__ xT, const unsigned* __restrict__ pos_h,
    const unsigned* __restrict__ pos_t, float* __restrict__ emb2) {
    __shared__ float rm[16384];   // XOR-swizzled copy: dst = i ^ ((i>>8)&31)
    for (int i = threadIdx.x; i < 16384; i += 1024) {
        float v = rmg[i];
        rm[i ^ ((i >> 8) & 31)] = v;
    }
    __syncthreads();
    const int wid = threadIdx.x >> 6, lane = threadIdx.x & 63;
    const int b = lane & 15, ig = lane >> 4;
    const int ntask = NGRP * 2;
    for (int task = blockIdx.x * 16 + wid; task < ntask; task += 256 * 16) {
        const int grp = task >> 1, role = task & 1;
        const int e = grp * 16 + b;
        const int node = role ? dst[e] : src[e];
        f32x4 h = emb_core(grp, role, b, ig, node, tbl, rm, xT);
        const unsigned pos = role ? pos_t[e] : pos_h[e];
        // 4 lanes (same b, ig=0..3) form one 64B block at queue position.
        f32x4* op = (f32x4*)(emb2 + (size_t)pos * 16);
        __builtin_nontemporal_store(h, op + ig);
    }
}

// ---- single-chunk path: streaming accumulate + sum-of-squares (no cv) ----
__global__ __launch_bounds__(1024) void k_accf(
    const unsigned* __restrict__ qbase, const unsigned* __restrict__ gq,
    const float* __restrict__ emb2, double* __restrict__ acc) {
    __shared__ float cvs[CHUNK * 17];    // stride 17: conflict-free ds atomics
    __shared__ double red[16];
    for (int i = threadIdx.x; i < CHUNK * 17; i += 1024) cvs[i] = 0.0f;
    __syncthreads();
    int o = blockIdx.x;
    unsigned lo = qbase[o], hi = qbase[o + 1];
    for (unsigned it = lo + threadIdx.x; it < hi; it += 1024) {
        unsigned ent = gq[it];
        unsigned ln = (ent >> 19) & 511u, role = ent >> 28;
        const f32x4* ep = (const f32x4*)(emb2 + (size_t)it * 16);   // SEQUENTIAL
        float sgn = role ? -1.0f : 1.0f;
        float* c = cvs + ln * 17;
#pragma unroll
        for (int k4 = 0; k4 < 4; ++k4) {
            f32x4 v = __builtin_nontemporal_load(ep + k4);
            atomicAdd(&c[k4*4+0], sgn * v[0]);
            atomicAdd(&c[k4*4+1], sgn * v[1]);
            atomicAdd(&c[k4*4+2], sgn * v[2]);
            atomicAdd(&c[k4*4+3], sgn * v[3]);
        }
    }
    __syncthreads();
    double p = 0.0;
    for (int idx = threadIdx.x; idx < CHUNK * 16; idx += 1024) {
        float v = cvs[(idx >> 4) * 17 + (idx & 15)];
        p += (double)v * v;
    }
#pragma unroll
    for (int off = 32; off > 0; off >>= 1) p += __shfl_down(p, off, 64);
    int wv = threadIdx.x >> 6;
    if ((threadIdx.x & 63) == 0) red[wv] = p;
    __syncthreads();
    if (threadIdx.x == 0) {
        double t2 = 0.0;
#pragma unroll
        for (int i = 0; i < 16; ++i) t2 += red[i];
        atomicAdd(acc, t2);
    }
}

// ================== chunked fallback path (round-5 behavior) ==================
__global__ __launch_bounds__(1024) void k_emb(
    const int* __restrict__ src, const int* __restrict__ dst,
    const unsigned char* __restrict__ tbl, const float* __restrict__ rmg,
    const float* __restrict__ xT, float* __restrict__ emb,
    int g0, int ng, int ECe) {
    __shared__ float rm[16384];
    for (int i = threadIdx.x; i < 16384; i += 1024) {
        float v = rmg[i];
        rm[i ^ ((i >> 8) & 31)] = v;
    }
    __syncthreads();
    const int wid = threadIdx.x >> 6, lane = threadIdx.x & 63;
    const int b = lane & 15, ig = lane >> 4;
    const int ntask = ng * 2;
    for (int task = blockIdx.x * 16 + wid; task < ntask; task += 256 * 16) {
        const int lgrp = task >> 1, role = task & 1;
        const int grp = g0 + lgrp;
        const int e = grp * 16 + b;
        const int node = role ? dst[e] : src[e];
        f32x4 h = emb_core(grp, role, b, ig, node, tbl, rm, xT);
        const int le = lgrp * 16 + b;
        f32x4* op = (f32x4*)(emb + ((size_t)role * ECe + le) * 16);
        op[ig] = h;
    }
}

__global__ __launch_bounds__(1024) void k_acc(
    const unsigned* __restrict__ qbase, const unsigned* __restrict__ gq,
    const float* __restrict__ emb, float* __restrict__ cv,
    int elo, int cnt, int ECe) {
    __shared__ float cvs[CHUNK * 17];
    int o = blockIdx.x;
    int nbase = o * CHUNK;
    for (int idx = threadIdx.x; idx < CHUNK * 16; idx += 1024)
        cvs[(idx >> 4) * 17 + (idx & 15)] = cv[nbase * 16 + idx];
    __syncthreads();
    unsigned lo = qbase[o], hi = qbase[o + 1];
    for (unsigned it = lo + threadIdx.x; it < hi; it += 1024) {
        unsigned ent = gq[it];
        unsigned e = ent & 0x7FFFFu;
        if ((unsigned)(e - (unsigned)elo) >= (unsigned)cnt) continue;
        unsigned ln = (ent >> 19) & 511u, role = ent >> 28;
        unsigned le = e - (unsigned)elo;
        const float4* ep = (const float4*)(emb + ((size_t)role * ECe + le) * 16);
        float sgn = role ? -1.0f : 1.0f;
        float* c = cvs + ln * 17;
#pragma unroll
        for (int k4 = 0; k4 < 4; ++k4) {
            float4 v = ep[k4];
            atomicAdd(&c[k4*4+0], sgn * v.x);
            atomicAdd(&c[k4*4+1], sgn * v.y);
            atomicAdd(&c[k4*4+2], sgn * v.z);
            atomicAdd(&c[k4*4+3], sgn * v.w);
        }
    }
    __syncthreads();
    for (int idx = threadIdx.x; idx < CHUNK * 16; idx += 1024)
        cv[nbase * 16 + idx] = cvs[(idx >> 4) * 17 + (idx & 15)];
}

__global__ __launch_bounds__(256) void k_sq(const float* __restrict__ cv,
                                            double* __restrict__ acc) {
    __shared__ double red[4];
    int idx = blockIdx.x * 256 + (int)threadIdx.x;
    int stride = gridDim.x * 256;
    const int total4 = (16 * N_NODES) / 4;
    double p = 0.0;
    for (int i = idx; i < total4; i += stride) {
        float4 v = ((const float4*)cv)[i];
        p += (double)v.x * v.x + (double)v.y * v.y
           + (double)v.z * v.z + (double)v.w * v.w;
    }
#pragma unroll
    for (int off = 32; off > 0; off >>= 1) p += __shfl_down(p, off, 64);
    int w = threadIdx.x >> 6;
    if ((threadIdx.x & 63) == 0) red[w] = p;
    __syncthreads();
    if (threadIdx.x == 0)
        atomicAdd(acc, red[0] + red[1] + red[2] + red[3]);
}
// =============================================================================

__global__ void k_out(const double* __restrict__ acc, float* __restrict__ out) {
    out[0] = (float)acc[0];
}

extern "C" void kernel_launch(void* const* d_in, const int* in_sizes, int n_in,
                              void* d_out, int out_size, void* d_ws, size_t ws_size,
                              hipStream_t stream) {
    const float* reps = (const float*)d_in[0];   // [16, N]
    const float* rmg  = (const float*)d_in[1];   // [8,8,16,16]
    const int*   eidx = (const int*)d_in[2];     // [2, E]
    const int*   et   = (const int*)d_in[3];     // [N]
    const int* src = eidx;
    const int* dst = eidx + N_EDGES;

    char* ws = (char*)d_ws;
    double*        acc   = (double*)(ws + OFF_ACC);
    unsigned*      gcnt  = (unsigned*)(ws + OFF_GCNT);
    unsigned*      qbase = (unsigned*)(ws + OFF_QBASE);
    unsigned*      qcur  = (unsigned*)(ws + OFF_QCUR);
    float*         cv    = (float*)(ws + OFF_CV);
    unsigned char* tp    = (unsigned char*)(ws + OFF_TP);
    float*         xT    = (float*)(ws + OFF_XT);
    unsigned char* tbl   = (unsigned char*)(ws + OFF_TBL);
    unsigned*      gq    = (unsigned*)(ws + OFF_GQ);
    float*         emb   = (float*)(ws + OFF_EMB);

    const bool single = ws_size >= (size_t)OFF_EMB + EMB_BYTES;  // confirmed r6
    // pos arrays: single path -> unused cv slot; fallback -> scratch in emb area
    unsigned* pos_h = single ? (unsigned*)(ws + OFF_CV) : (unsigned*)(ws + OFF_EMB);
    unsigned* pos_t = pos_h + N_EDGES;

    (void)hipMemsetAsync(ws, 0, single ? 1024 : 6404096, stream);

    k_hist  <<<245, 1024, 0, stream>>>(src, dst, et, tp, gcnt);
    k_tbl   <<<NTBL / 256, 256, 0, stream>>>(tp, tbl);
    k_prefix<<<1, 256, 0, stream>>>(gcnt, qbase, qcur);
    k_place <<<245, 1024, 0, stream>>>(src, dst, qcur, gq, pos_h, pos_t);
    k_degxT <<<NOWN, 1024, 0, stream>>>(qbase, gq, reps, xT);

    if (single) {
        k_emb2<<<256, 1024, 0, stream>>>(src, dst, tbl, rmg, xT, pos_h, pos_t, emb);
        k_accf<<<NOWN, 1024, 0, stream>>>(qbase, gq, emb, acc);
    } else {
        size_t avail = (ws_size > (size_t)OFF_EMB) ? ws_size - (size_t)OFF_EMB : 2048;
        int ECg = (int)(avail / 2048);
        if (ECg < 1) ECg = 1;
        if (ECg > NGRP) ECg = NGRP;
        const int ECe = ECg * 16;
        for (int g0 = 0; g0 < NGRP; g0 += ECg) {
            int ng = (NGRP - g0 < ECg) ? (NGRP - g0) : ECg;
            k_emb<<<256, 1024, 0, stream>>>(src, dst, tbl, rmg, xT, emb, g0, ng, ECe);
            k_acc<<<NOWN, 1024, 0, stream>>>(qbase, gq, emb, cv, g0 * 16, ng * 16, ECe);
        }
        k_sq<<<256, 256, 0, stream>>>(cv, acc);
    }
    k_out<<<1, 1, 0, stream>>>(acc, (float*)d_out);
}

// Round 11
// 274.755 us; speedup vs baseline: 1.0073x; 1.0073x over previous
//
#include <hip/hip_runtime.h>
#include <math.h>

#define N_NODES 100000
#define N_EDGES 500000
#define NGRP    31250        // N_EDGES/16
#define NTBL    8000000      // NGRP * 256

#define CHUNK   400          // nodes per owner block
#define NOWN    250          // 250*400 = 100000 exactly

typedef float f32x4 __attribute__((ext_vector_type(4)));  // nontemporal-safe

// Workspace layout (bytes):
#define OFF_ACC   0          // double
#define OFF_GCNT  16         // uint[250]
#define OFF_QBASE 1024       // uint[251]
#define OFF_QCUR  2048       // uint[250]
#define OFF_CV    4096       // fallback: float[N][16] 6.4MB | single: pos_h/pos_t (4MB)
#define OFF_TP    6404096    // uchar[E]
#define OFF_XT    6904096    // float[N][16]  6.4MB
#define OFF_TBL   13304096   // uchar[8M]
#define OFF_GQ    21304096   // uint[1M]      4MB
#define OFF_EMB   25304096   // emb buffer (64MB in single-chunk path)
#define EMB_BYTES 64000000ull

__device__ __forceinline__ unsigned owner_of(int n) {
    // floor(n/400) = floor((n>>4)/25); magic /25
    return (unsigned)(((unsigned long long)((unsigned)n >> 4) * 1374389535ull) >> 35);
}

// ---- pass 1: per-owner incidence histogram (+ tp bytes) ----
__global__ __launch_bounds__(1024) void k_hist(
    const int* __restrict__ src, const int* __restrict__ dst,
    const int* __restrict__ et, unsigned char* __restrict__ tp,
    unsigned* __restrict__ gcnt) {
    __shared__ unsigned hist[NOWN];
    for (int i = threadIdx.x; i < NOWN; i += 1024) hist[i] = 0;
    __syncthreads();
    int base = blockIdx.x * 2048;
#pragma unroll
    for (int k = 0; k < 2; ++k) {
        int e = base + k * 1024 + (int)threadIdx.x;
        if (e < N_EDGES) {
            int s = src[e], d = dst[e];
            tp[e] = (unsigned char)(et[s] * 8 + et[d]);
            atomicAdd(&hist[owner_of(s)], 1u);
            atomicAdd(&hist[owner_of(d)], 1u);
        }
    }
    __syncthreads();
    for (int i = threadIdx.x; i < NOWN; i += 1024)
        if (hist[i]) atomicAdd(&gcnt[i], hist[i]);
}

// ---- exclusive prefix over 250 counts ----
__global__ void k_prefix(const unsigned* __restrict__ gcnt,
                         unsigned* __restrict__ qbase, unsigned* __restrict__ qcur) {
    __shared__ unsigned v[256];
    int t = threadIdx.x;
    v[t] = (t < NOWN) ? gcnt[t] : 0u;
    __syncthreads();
    unsigned my = v[t];
#pragma unroll
    for (int off = 1; off < 256; off <<= 1) {
        unsigned add = (t >= off) ? v[t - off] : 0u;
        __syncthreads();
        v[t] += add;
        __syncthreads();
    }
    if (t < NOWN) {
        unsigned excl = v[t] - my;
        qbase[t] = excl; qcur[t] = excl;
    }
    if (t == NOWN) qbase[NOWN] = v[NOWN - 1];
}

// ---- pass 2: place incidences; record each incidence's queue position ----
__global__ __launch_bounds__(1024) void k_place(
    const int* __restrict__ src, const int* __restrict__ dst,
    unsigned* __restrict__ qcur, unsigned* __restrict__ gq,
    unsigned* __restrict__ pos_h, unsigned* __restrict__ pos_t) {
    __shared__ unsigned hist[NOWN];
    __shared__ unsigned lcur[NOWN];
    for (int i = threadIdx.x; i < NOWN; i += 1024) hist[i] = 0;
    __syncthreads();
    int base = blockIdx.x * 2048;
#pragma unroll
    for (int k = 0; k < 2; ++k) {
        int e = base + k * 1024 + (int)threadIdx.x;
        if (e < N_EDGES) {
            atomicAdd(&hist[owner_of(src[e])], 1u);
            atomicAdd(&hist[owner_of(dst[e])], 1u);
        }
    }
    __syncthreads();
    for (int i = threadIdx.x; i < NOWN; i += 1024)
        lcur[i] = hist[i] ? atomicAdd(&qcur[i], hist[i]) : 0u;
    __syncthreads();
#pragma unroll
    for (int k = 0; k < 2; ++k) {
        int e = base + k * 1024 + (int)threadIdx.x;
        if (e < N_EDGES) {
            int s = src[e], d = dst[e];
            unsigned os = owner_of(s), od = owner_of(d);
            unsigned ps = atomicAdd(&lcur[os], 1u);
            gq[ps] = (unsigned)e | ((unsigned)(s - (int)os * CHUNK) << 19);
            pos_h[e] = ps;
            unsigned pd = atomicAdd(&lcur[od], 1u);
            gq[pd] = (unsigned)e | ((unsigned)(d - (int)od * CHUNK) << 19) | (1u << 28);
            pos_t[e] = pd;
        }
    }
}

// ---- per-owner: deg from tail entries, then xT = reps * deg^-1/2 ----
__global__ __launch_bounds__(1024) void k_degxT(
    const unsigned* __restrict__ qbase, const unsigned* __restrict__ gq,
    const float* __restrict__ reps, float* __restrict__ xT) {
    __shared__ unsigned dh[CHUNK];
    for (int i = threadIdx.x; i < CHUNK; i += 1024) dh[i] = 0;
    __syncthreads();
    int o = blockIdx.x;
    unsigned lo = qbase[o], hi = qbase[o + 1];
    for (unsigned i = lo + threadIdx.x; i < hi; i += 1024) {
        unsigned ent = gq[i];
        if (ent >> 28) atomicAdd(&dh[(ent >> 19) & 511u], 1u);
    }
    __syncthreads();
    int nbase = o * CHUNK;
    for (int idx = threadIdx.x; idx < CHUNK; idx += 1024) {
        int n = nbase + idx;
        unsigned dg = dh[idx];
        float inv = dg ? 1.0f / sqrtf((float)dg) : 0.0f;
        float v[16];
#pragma unroll
        for (int j = 0; j < 16; ++j) v[j] = reps[j * N_NODES + n] * inv;
        float4* outp = (float4*)(xT + (size_t)n * 16);
#pragma unroll
        for (int j4 = 0; j4 < 4; ++j4)
            outp[j4] = make_float4(v[4*j4], v[4*j4+1], v[4*j4+2], v[4*j4+3]);
    }
}

// ---- tbl[E4][q] = tp[e2(q,E4)]:  u = 2q+E4; e2 = 1953q + (u>>4) ----
__global__ __launch_bounds__(256) void k_tbl(const unsigned char* __restrict__ tp,
                                             unsigned char* __restrict__ tbl) {
    int idx = blockIdx.x * 256 + (int)threadIdx.x;
    int E4 = idx >> 8, q = idx & 255;
    int u = 2 * q + E4;
    int e2 = 1953 * q + (u >> 4);
    tbl[idx] = tp[e2];
}

// ---- shared core of the wave-cooperative embedding ----
// head_maps[i,j,e] = RM[t][a][b]; q=16i+j, b=e&15, a=(2j+grp)&15, t=tbl[grp][q]
// (tail: byte-swapped t, x from dst). Wave: lanes=(b, ig), lane's i = 4*ig+ip.
__device__ __forceinline__ f32x4 emb_core(
    int grp, int role, int b, int ig, int node,
    const unsigned char* __restrict__ tbl, const float* __restrict__ rm,
    const float* __restrict__ xT) {
    float xs[16];
    const float4* xp = (const float4*)(xT + (size_t)node * 16);
#pragma unroll
    for (int j4 = 0; j4 < 4; ++j4) {
        float4 v = xp[j4];
        xs[4*j4] = v.x; xs[4*j4+1] = v.y; xs[4*j4+2] = v.z; xs[4*j4+3] = v.w;
    }
    unsigned w[16];
    const uint4* tr4 = (const uint4*)(tbl + (size_t)grp * 256 + ig * 64);
#pragma unroll
    for (int ip = 0; ip < 4; ++ip) {
        uint4 u = tr4[ip];
        w[ip*4+0] = u.x; w[ip*4+1] = u.y; w[ip*4+2] = u.z; w[ip*4+3] = u.w;
    }
    if (role) {   // byte-parallel type-pair swap: t' = ((t&7)<<3)|(t>>3)
#pragma unroll
        for (int c = 0; c < 16; ++c)
            w[c] = ((w[c] & 0x07070707u) << 3) | ((w[c] >> 3) & 0x07070707u);
    }
    unsigned vab[16];
#pragma unroll
    for (int jj = 0; jj < 16; ++jj)
        vab[jj] = ((unsigned)((2 * jj + grp) & 15) << 4) | (unsigned)b;

    f32x4 h;
#pragma unroll
    for (int ip = 0; ip < 4; ++ip) {
        float hacc = 0.f;
#pragma unroll
        for (int jj = 0; jj < 16; ++jj) {
            unsigned t = (w[ip*4 + (jj >> 2)] >> ((jj & 3) * 8)) & 255u;
            unsigned idx = ((t << 8) + vab[jj]) ^ (t & 31u);
            hacc += rm[idx] * xs[jj];
        }
        h[ip] = hacc;
    }
    return h;
}

// ---- single-chunk path: embeddings stored at their QUEUE POSITION ----
__global__ __launch_bounds__(1024) void k_emb2(
    const int* __restrict__ src, const int* __restrict__ dst,
    const unsigned char* __restrict__ tbl, const float* __restrict__ rmg,
    const float* __restrict__ xT, const unsigned* __restrict__ pos_h,
    const unsigned* __restrict__ pos_t, float* __restrict__ emb2) {
    __shared__ float rm[16384];   // XOR-swizzled copy: dst = i ^ ((i>>8)&31)
    for (int i = threadIdx.x; i < 16384; i += 1024) {
        float v = rmg[i];
        rm[i ^ ((i >> 8) & 31)] = v;
    }
    __syncthreads();
    const int wid = threadIdx.x >> 6, lane = threadIdx.x & 63;
    const int b = lane & 15, ig = lane >> 4;
    const int ntask = NGRP * 2;
    for (int task = blockIdx.x * 16 + wid; task < ntask; task += 256 * 16) {
        const int grp = task >> 1, role = task & 1;
        const int e = grp * 16 + b;
        const int node = role ? dst[e] : src[e];
        f32x4 h = emb_core(grp, role, b, ig, node, tbl, rm, xT);
        const unsigned pos = role ? pos_t[e] : pos_h[e];
        // 4 lanes (same b, ig=0..3) form one 64B block at queue position.
        f32x4* op = (f32x4*)(emb2 + (size_t)pos * 16);
        __builtin_nontemporal_store(h, op + ig);
    }
}

// ---- single-chunk path: streaming accumulate + sum-of-squares (no cv) ----
// MLP fix (r11): batch 4 incidences/thread, issue all loads (plain, cacheable)
// before any LDS atomic; all array indices compile-time (no scratch).
__global__ __launch_bounds__(1024) void k_accf(
    const unsigned* __restrict__ qbase, const unsigned* __restrict__ gq,
    const float* __restrict__ emb2, double* __restrict__ acc) {
    __shared__ float cvs[CHUNK * 17];    // stride 17: conflict-free ds atomics
    __shared__ double red[16];
    for (int i = threadIdx.x; i < CHUNK * 17; i += 1024) cvs[i] = 0.0f;
    __syncthreads();
    int o = blockIdx.x;
    unsigned lo = qbase[o], hi = qbase[o + 1];
    for (unsigned base = lo + threadIdx.x; base < hi; base += 4096u) {
        unsigned ents[4];
        f32x4 vv0[4], vv1[4], vv2[4], vv3[4];
        // phase 1: issue every load (up to 4 gq + 16 x 16B emb2)
#pragma unroll
        for (int k = 0; k < 4; ++k) {
            unsigned it = base + (unsigned)k * 1024u;
            if (it < hi) {
                ents[k] = gq[it];
                const f32x4* ep = (const f32x4*)(emb2 + (size_t)it * 16);
                vv0[k] = ep[0]; vv1[k] = ep[1]; vv2[k] = ep[2]; vv3[k] = ep[3];
            }
        }
        // phase 2: consume into LDS
#pragma unroll
        for (int k = 0; k < 4; ++k) {
            unsigned it = base + (unsigned)k * 1024u;
            if (it < hi) {
                unsigned ent = ents[k];
                unsigned ln = (ent >> 19) & 511u, role = ent >> 28;
                float sgn = role ? -1.0f : 1.0f;
                float* c = cvs + ln * 17;
#pragma unroll
                for (int j = 0; j < 4; ++j) atomicAdd(&c[j],      sgn * vv0[k][j]);
#pragma unroll
                for (int j = 0; j < 4; ++j) atomicAdd(&c[4 + j],  sgn * vv1[k][j]);
#pragma unroll
                for (int j = 0; j < 4; ++j) atomicAdd(&c[8 + j],  sgn * vv2[k][j]);
#pragma unroll
                for (int j = 0; j < 4; ++j) atomicAdd(&c[12 + j], sgn * vv3[k][j]);
            }
        }
    }
    __syncthreads();
    double p = 0.0;
    for (int idx = threadIdx.x; idx < CHUNK * 16; idx += 1024) {
        float v = cvs[(idx >> 4) * 17 + (idx & 15)];
        p += (double)v * v;
    }
#pragma unroll
    for (int off = 32; off > 0; off >>= 1) p += __shfl_down(p, off, 64);
    int wv = threadIdx.x >> 6;
    if ((threadIdx.x & 63) == 0) red[wv] = p;
    __syncthreads();
    if (threadIdx.x == 0) {
        double t2 = 0.0;
#pragma unroll
        for (int i = 0; i < 16; ++i) t2 += red[i];
        atomicAdd(acc, t2);
    }
}

// ================== chunked fallback path (round-5 behavior) ==================
__global__ __launch_bounds__(1024) void k_emb(
    const int* __restrict__ src, const int* __restrict__ dst,
    const unsigned char* __restrict__ tbl, const float* __restrict__ rmg,
    const float* __restrict__ xT, float* __restrict__ emb,
    int g0, int ng, int ECe) {
    __shared__ float rm[16384];
    for (int i = threadIdx.x; i < 16384; i += 1024) {
        float v = rmg[i];
        rm[i ^ ((i >> 8) & 31)] = v;
    }
    __syncthreads();
    const int wid = threadIdx.x >> 6, lane = threadIdx.x & 63;
    const int b = lane & 15, ig = lane >> 4;
    const int ntask = ng * 2;
    for (int task = blockIdx.x * 16 + wid; task < ntask; task += 256 * 16) {
        const int lgrp = task >> 1, role = task & 1;
        const int grp = g0 + lgrp;
        const int e = grp * 16 + b;
        const int node = role ? dst[e] : src[e];
        f32x4 h = emb_core(grp, role, b, ig, node, tbl, rm, xT);
        const int le = lgrp * 16 + b;
        f32x4* op = (f32x4*)(emb + ((size_t)role * ECe + le) * 16);
        op[ig] = h;
    }
}

__global__ __launch_bounds__(1024) void k_acc(
    const unsigned* __restrict__ qbase, const unsigned* __restrict__ gq,
    const float* __restrict__ emb, float* __restrict__ cv,
    int elo, int cnt, int ECe) {
    __shared__ float cvs[CHUNK * 17];
    int o = blockIdx.x;
    int nbase = o * CHUNK;
    for (int idx = threadIdx.x; idx < CHUNK * 16; idx += 1024)
        cvs[(idx >> 4) * 17 + (idx & 15)] = cv[nbase * 16 + idx];
    __syncthreads();
    unsigned lo = qbase[o], hi = qbase[o + 1];
    for (unsigned it = lo + threadIdx.x; it < hi; it += 1024) {
        unsigned ent = gq[it];
        unsigned e = ent & 0x7FFFFu;
        if ((unsigned)(e - (unsigned)elo) >= (unsigned)cnt) continue;
        unsigned ln = (ent >> 19) & 511u, role = ent >> 28;
        unsigned le = e - (unsigned)elo;
        const float4* ep = (const float4*)(emb + ((size_t)role * ECe + le) * 16);
        float sgn = role ? -1.0f : 1.0f;
        float* c = cvs + ln * 17;
#pragma unroll
        for (int k4 = 0; k4 < 4; ++k4) {
            float4 v = ep[k4];
            atomicAdd(&c[k4*4+0], sgn * v.x);
            atomicAdd(&c[k4*4+1], sgn * v.y);
            atomicAdd(&c[k4*4+2], sgn * v.z);
            atomicAdd(&c[k4*4+3], sgn * v.w);
        }
    }
    __syncthreads();
    for (int idx = threadIdx.x; idx < CHUNK * 16; idx += 1024)
        cv[nbase * 16 + idx] = cvs[(idx >> 4) * 17 + (idx & 15)];
}

__global__ __launch_bounds__(256) void k_sq(const float* __restrict__ cv,
                                            double* __restrict__ acc) {
    __shared__ double red[4];
    int idx = blockIdx.x * 256 + (int)threadIdx.x;
    int stride = gridDim.x * 256;
    const int total4 = (16 * N_NODES) / 4;
    double p = 0.0;
    for (int i = idx; i < total4; i += stride) {
        float4 v = ((const float4*)cv)[i];
        p += (double)v.x * v.x + (double)v.y * v.y
           + (double)v.z * v.z + (double)v.w * v.w;
    }
#pragma unroll
    for (int off = 32; off > 0; off >>= 1) p += __shfl_down(p, off, 64);
    int w = threadIdx.x >> 6;
    if ((threadIdx.x & 63) == 0) red[w] = p;
    __syncthreads();
    if (threadIdx.x == 0)
        atomicAdd(acc, red[0] + red[1] + red[2] + red[3]);
}
// =============================================================================

__global__ void k_out(const double* __restrict__ acc, float* __restrict__ out) {
    out[0] = (float)acc[0];
}

extern "C" void kernel_launch(void* const* d_in, const int* in_sizes, int n_in,
                              void* d_out, int out_size, void* d_ws, size_t ws_size,
                              hipStream_t stream) {
    const float* reps = (const float*)d_in[0];   // [16, N]
    const float* rmg  = (const float*)d_in[1];   // [8,8,16,16]
    const int*   eidx = (const int*)d_in[2];     // [2, E]
    const int*   et   = (const int*)d_in[3];     // [N]
    const int* src = eidx;
    const int* dst = eidx + N_EDGES;

    char* ws = (char*)d_ws;
    double*        acc   = (double*)(ws + OFF_ACC);
    unsigned*      gcnt  = (unsigned*)(ws + OFF_GCNT);
    unsigned*      qbase = (unsigned*)(ws + OFF_QBASE);
    unsigned*      qcur  = (unsigned*)(ws + OFF_QCUR);
    float*         cv    = (float*)(ws + OFF_CV);
    unsigned char* tp    = (unsigned char*)(ws + OFF_TP);
    float*         xT    = (float*)(ws + OFF_XT);
    unsigned char* tbl   = (unsigned char*)(ws + OFF_TBL);
    unsigned*      gq    = (unsigned*)(ws + OFF_GQ);
    float*         emb   = (float*)(ws + OFF_EMB);

    const bool single = ws_size >= (size_t)OFF_EMB + EMB_BYTES;  // confirmed r6
    // pos arrays: single path -> unused cv slot; fallback -> scratch in emb area
    unsigned* pos_h = single ? (unsigned*)(ws + OFF_CV) : (unsigned*)(ws + OFF_EMB);
    unsigned* pos_t = pos_h + N_EDGES;

    (void)hipMemsetAsync(ws, 0, single ? 1024 : 6404096, stream);

    k_hist  <<<245, 1024, 0, stream>>>(src, dst, et, tp, gcnt);
    k_tbl   <<<NTBL / 256, 256, 0, stream>>>(tp, tbl);
    k_prefix<<<1, 256, 0, stream>>>(gcnt, qbase, qcur);
    k_place <<<245, 1024, 0, stream>>>(src, dst, qcur, gq, pos_h, pos_t);
    k_degxT <<<NOWN, 1024, 0, stream>>>(qbase, gq, reps, xT);

    if (single) {
        k_emb2<<<256, 1024, 0, stream>>>(src, dst, tbl, rmg, xT, pos_h, pos_t, emb);
        k_accf<<<NOWN, 1024, 0, stream>>>(qbase, gq, emb, acc);
    } else {
        size_t avail = (ws_size > (size_t)OFF_EMB) ? ws_size - (size_t)OFF_EMB : 2048;
        int ECg = (int)(avail / 2048);
        if (ECg < 1) ECg = 1;
        if (ECg > NGRP) ECg = NGRP;
        const int ECe = ECg * 16;
        for (int g0 = 0; g0 < NGRP; g0 += ECg) {
            int ng = (NGRP - g0 < ECg) ? (NGRP - g0) : ECg;
            k_emb<<<256, 1024, 0, stream>>>(src, dst, tbl, rmg, xT, emb, g0, ng, ECe);
            k_acc<<<NOWN, 1024, 0, stream>>>(qbase, gq, emb, cv, g0 * 16, ng * 16, ECe);
        }
        k_sq<<<256, 256, 0, stream>>>(cv, acc);
    }
    k_out<<<1, 1, 0, stream>>>(acc, (float*)d_out);
}